// Round 8
// baseline (252.441 us; speedup 1.0000x reference)
//
#include <hip/hip_runtime.h>
#include <hip/hip_cooperative_groups.h>

namespace cg = cooperative_groups;

typedef __bf16 bf16x8 __attribute__((ext_vector_type(8)));
typedef float floatx4 __attribute__((ext_vector_type(4)));

// split fp32 -> bf16 hi + bf16 lo (x ~= hi + lo, residual ~2^-17)
__device__ inline void cvt8_hl(const float* __restrict__ p, bf16x8& h, bf16x8& l){
  float4 v0 = *reinterpret_cast<const float4*>(p);
  float4 v1 = *reinterpret_cast<const float4*>(p + 4);
  float v[8] = {v0.x, v0.y, v0.z, v0.w, v1.x, v1.y, v1.z, v1.w};
  #pragma unroll
  for (int i = 0; i < 8; ++i) {
    __bf16 hi = (__bf16)v[i];
    h[i] = hi;
    l[i] = (__bf16)(v[i] - (float)hi);
  }
}

// ---------------------------------------------------------------------------
// K1 (round-0 proven, byte-identical; ~31us). ILP > TLP for this workload
// (R1/R3/R5 post-mortems). Do not touch.
// ---------------------------------------------------------------------------
__global__ __launch_bounds__(256) void k1_gemm(
    const float* __restrict__ x,
    const float* __restrict__ Wt,
    const float* __restrict__ Wg,
    float* __restrict__ mod)
{
  __shared__ float red[3][32][64];   // waves 1..3 partials, 24 KB
  const int tid  = threadIdx.x;
  const int wave = tid >> 6, lane = tid & 63;
  const int quad = lane >> 4, r16 = lane & 15;
  const int ff = blockIdx.x * 16 + r16;
  const int kb = wave * 256 + quad * 8;

  floatx4 accT[4], accG[4];
  #pragma unroll
  for (int m = 0; m < 4; ++m) { accT[m] = (floatx4)0.0f; accG[m] = (floatx4)0.0f; }

  const float* wt = Wt + ff * 1024 + kb;
  const float* wg = Wg + ff * 1024 + kb;
  const float* xp = x  + r16 * 1024 + kb;

  #pragma unroll
  for (int it = 0; it < 8; ++it) {
    const int ko = it * 32;
    bf16x8 bth, btl, bgh, bgl;
    cvt8_hl(wt + ko, bth, btl);
    cvt8_hl(wg + ko, bgh, bgl);
    #pragma unroll
    for (int mt = 0; mt < 4; ++mt) {
      bf16x8 ah, al;
      cvt8_hl(xp + mt * 16384 + ko, ah, al);
      accT[mt] = __builtin_amdgcn_mfma_f32_16x16x32_bf16(ah, bth, accT[mt], 0, 0, 0);
      accT[mt] = __builtin_amdgcn_mfma_f32_16x16x32_bf16(ah, btl, accT[mt], 0, 0, 0);
      accT[mt] = __builtin_amdgcn_mfma_f32_16x16x32_bf16(al, bth, accT[mt], 0, 0, 0);
      accG[mt] = __builtin_amdgcn_mfma_f32_16x16x32_bf16(ah, bgh, accG[mt], 0, 0, 0);
      accG[mt] = __builtin_amdgcn_mfma_f32_16x16x32_bf16(ah, bgl, accG[mt], 0, 0, 0);
      accG[mt] = __builtin_amdgcn_mfma_f32_16x16x32_bf16(al, bgh, accG[mt], 0, 0, 0);
    }
  }

  if (wave != 0) {
    #pragma unroll
    for (int mt = 0; mt < 4; ++mt)
      #pragma unroll
      for (int r = 0; r < 4; ++r) {
        red[wave - 1][mt * 4 + r][lane]      = accT[mt][r];
        red[wave - 1][16 + mt * 4 + r][lane] = accG[mt][r];
      }
  }
  __syncthreads();
  if (wave == 0) {
    #pragma unroll
    for (int mt = 0; mt < 4; ++mt) {
      #pragma unroll
      for (int r = 0; r < 4; ++r) {
        float t = accT[mt][r] + red[0][mt * 4 + r][lane]
                              + red[1][mt * 4 + r][lane]
                              + red[2][mt * 4 + r][lane];
        float g = accG[mt][r] + red[0][16 + mt * 4 + r][lane]
                              + red[1][16 + mt * 4 + r][lane]
                              + red[2][16 + mt * 4 + r][lane];
        float sig = 1.0f / (1.0f + __expf(-g));
        int b = mt * 16 + quad * 4 + r;          // C/D: row = quad*4 + reg
        mod[b * 8192 + ff] = t * g * sig;
      }
    }
  }
}

// ---------------------------------------------------------------------------
// K234: fused k1b + k2 + k4 as ONE cooperative kernel, grid 512 x 256
// (2 blocks/CU, 4.2 KB LDS -> co-residency trivially satisfied).
// R0-R7 evidence: k2+k4 cost ~75-85us invariant to every internal
// restructuring while intrinsic work is ~5us => per-dispatch overhead
// (launch gaps + post-poison cold ramp) dominates. Fusing collapses three
// dispatches into one; phase bodies are the PROVEN R4-k2 / R0-k4 internals
// with identical numerics; grid.sync() between phases.
// ---------------------------------------------------------------------------
__global__ __launch_bounds__(256) void k234(
    const float* __restrict__ mod,
    float* __restrict__ sums,        // [256] raw |mod| row sums (pre-zeroed)
    const float* __restrict__ wstat,
    const float* __restrict__ wmod,
    const float* __restrict__ cw,
    const float* __restrict__ cb,
    float* __restrict__ partial,     // [512] mag partials (pre-zeroed)
    float* __restrict__ out)
{
  const int bid = blockIdx.x;
  const int tid = threadIdx.x;
  const int wave = tid >> 6;

  __shared__ float ls[4];
  __shared__ __align__(16) float a2l[64 * 8];   // phase-1 a-tile
  __shared__ __align__(16) float a4l[32 * 16];  // phase-2 a-tile

  float weff[4]; float beff = 0.0f;
  #pragma unroll
  for (int r = 0; r < 4; ++r) {
    weff[r] = cw[r] + cw[4 + r] + cw[8 + r] + cw[12 + r];
    beff += cb[r];
  }

  // ---- phase 0: |mod| row sums (k1b). 512 blocks = 256 rows x 2 halves ----
  {
    const int row = bid >> 1, half = bid & 1;
    const float4 v = *reinterpret_cast<const float4*>(
        mod + row * 2048 + half * 1024 + tid * 4);
    float sum = fabsf(v.x) + fabsf(v.y) + fabsf(v.z) + fabsf(v.w);
    #pragma unroll
    for (int o = 1; o < 64; o <<= 1) sum += __shfl_xor(sum, o, 64);
    if ((tid & 63) == 0) ls[wave] = sum;
    __syncthreads();
    if (tid == 0) atomicAdd(&sums[row], ls[0] + ls[1] + ls[2] + ls[3]);
  }
  cg::this_grid().sync();

  // ---- phase 1: mag partial sums (R4-k2 internals). bid = (jc<<6)|b ----
  {
    const int b = bid & 63, jc = bid >> 6;
    const float s0 = rsqrtf(sums[b * 4 + 0] * (1.0f / 2048.0f) + 1e-4f);
    const float s1 = rsqrtf(sums[b * 4 + 1] * (1.0f / 2048.0f) + 1e-4f);
    const float* mb = mod + b * 8192;
    const int j = jc * 32 + (tid & 31);
    float bp[8];
    #pragma unroll
    for (int p = 0; p < 8; ++p) {
      int k = p >> 2, r = p & 3;
      bp[p] = mb[k * 2048 + r * 512 + 256 + j] * (k ? s1 : s0);
    }
    float accv = 0.0f;
    for (int isp = 0; isp < 4; ++isp) {
      __syncthreads();                       // protect a2l reuse
      #pragma unroll
      for (int q = 0; q < 2; ++q) {
        int e = q * 256 + tid;
        int il = e & 63, p = e >> 6;
        int k = p >> 2, r = p & 3;
        a2l[il * 8 + p] = mb[k * 2048 + r * 512 + isp * 64 + il]
                          * ((k ? s1 : s0) * weff[r]);
      }
      __syncthreads();
      const int ioff = tid >> 5;
      #pragma unroll
      for (int it = 0; it < 8; ++it) {
        const int il = it * 8 + ioff;
        const int i = isp * 64 + il;
        const float4 av0 = *reinterpret_cast<const float4*>(&a2l[il * 8]);
        const float4 av1 = *reinterpret_cast<const float4*>(&a2l[il * 8 + 4]);
        float d0 = av0.x * bp[0] + av0.y * bp[1] + av0.z * bp[2] + av0.w * bp[3];
        float d1 = av1.x * bp[4] + av1.y * bp[5] + av1.z * bp[6] + av1.w * bp[7];
        const int ij = i * 256 + j;
        float m0 = wmod[ij] * (d0 + beff);
        float m1 = wmod[65536 + ij] * (d1 + beff);
        float2 a1 = *reinterpret_cast<const float2*>(wstat + 131072 + ij * 2);
        float re = a1.x * m0 - a1.y * m1;
        float im = a1.x * m1 - a1.y * m0;
        accv += sqrtf(re * re + im * im + 1e-4f);
      }
    }
    #pragma unroll
    for (int o = 1; o < 64; o <<= 1) accv += __shfl_xor(accv, o, 64);
    __syncthreads();
    if ((tid & 63) == 0) ls[wave] = accv;
    __syncthreads();
    if (tid == 0) atomicAdd(&partial[b * 8 + jc], ls[0] + ls[1] + ls[2] + ls[3]);
  }
  cg::this_grid().sync();

  // ---- phase 2: final output (R0-k4 internals). bid = (islab<<6)|b ----
  {
    const int b = bid & 63, ibase = (bid >> 6) * 32;
    const float* mb = mod + b * 8192;
    float sk[4];
    #pragma unroll
    for (int k = 0; k < 4; ++k)
      sk[k] = rsqrtf(sums[b * 4 + k] * (1.0f / 2048.0f) + 1e-4f);
    float tot = 0.0f;
    #pragma unroll
    for (int t = 0; t < 8; ++t) tot += partial[b * 8 + t];
    const float inv = rsqrtf(tot * (1.0f / 65536.0f) + 1e-4f);

    #pragma unroll
    for (int p = 0; p < 2; ++p) {
      int idx = p * 256 + tid;
      int il = idx & 31, kr = idx >> 5;
      int k = kr >> 2, r = kr & 3;
      a4l[il * 16 + kr] = mb[k * 2048 + r * 512 + ibase + il] * (sk[k] * weff[r]);
    }
    const int j = (tid & 127) * 2;
    const int ioff = tid >> 7;
    float bp0[16], bp1[16];
    #pragma unroll
    for (int kr = 0; kr < 16; ++kr) {
      int k = kr >> 2, r = kr & 3;
      float2 v = *reinterpret_cast<const float2*>(mb + k * 2048 + r * 512 + 256 + j);
      bp0[kr] = v.x * sk[k]; bp1[kr] = v.y * sk[k];
    }
    __syncthreads();

    #pragma unroll 2
    for (int it = 0; it < 16; ++it) {
      const int il = it * 2 + ioff;
      const int i = ibase + il;
      const float4 a0 = *reinterpret_cast<const float4*>(&a4l[il * 16]);
      const float4 a1 = *reinterpret_cast<const float4*>(&a4l[il * 16 + 4]);
      const float4 a2 = *reinterpret_cast<const float4*>(&a4l[il * 16 + 8]);
      const float4 a3 = *reinterpret_cast<const float4*>(&a4l[il * 16 + 12]);
      const int ij = i * 256 + j;
      const float2 wm0 = *reinterpret_cast<const float2*>(wmod + ij);
      const float2 wm1 = *reinterpret_cast<const float2*>(wmod + 65536 + ij);
      const float2 wm2 = *reinterpret_cast<const float2*>(wmod + 131072 + ij);
      const float2 wm3 = *reinterpret_cast<const float2*>(wmod + 196608 + ij);
      const float4 A0v = *reinterpret_cast<const float4*>(wstat + ij * 2);
      const float4 A1v = *reinterpret_cast<const float4*>(wstat + 131072 + ij * 2);
      float outv[2];
      #pragma unroll
      for (int e = 0; e < 2; ++e) {
        const float* bp = e ? bp1 : bp0;
        float d0 = a0.x * bp[0] + a0.y * bp[1] + a0.z * bp[2] + a0.w * bp[3];
        float d1 = a1.x * bp[4] + a1.y * bp[5] + a1.z * bp[6] + a1.w * bp[7];
        float d2 = a2.x * bp[8] + a2.y * bp[9] + a2.z * bp[10] + a2.w * bp[11];
        float d3 = a3.x * bp[12] + a3.y * bp[13] + a3.z * bp[14] + a3.w * bp[15];
        float m0 = (e ? wm0.y : wm0.x) * (d0 + beff);
        float m1 = (e ? wm1.y : wm1.x) * (d1 + beff);
        float m2 = (e ? wm2.y : wm2.x) * (d2 + beff);
        float m3 = (e ? wm3.y : wm3.x) * (d3 + beff);
        float A0r = e ? A0v.z : A0v.x;
        float A0i = e ? A0v.w : A0v.y;
        float A1r = e ? A1v.z : A1v.x;
        float A1i = e ? A1v.w : A1v.y;
        float re = A1r * m0 - A1i * m1;
        float im = A1r * m1 - A1i * m0;
        float mwre = A0r + re * inv;
        float mwim = A0i + im * inv;
        float rd = rsqrtf(m2 * m2 + m3 * m3 + 1e-4f);
        outv[e] = (mwre * m2 + mwim * m3) * rd;
      }
      *reinterpret_cast<float2*>(out + b * 65536 + ij) = make_float2(outv[0], outv[1]);
    }
  }
}

extern "C" void kernel_launch(void* const* d_in, const int* in_sizes, int n_in,
                              void* d_out, int out_size, void* d_ws, size_t ws_size,
                              hipStream_t stream) {
  const float* x     = (const float*)d_in[0];
  const float* Wt    = (const float*)d_in[1];
  const float* Wg    = (const float*)d_in[2];
  const float* wstat = (const float*)d_in[3];
  const float* wmod  = (const float*)d_in[4];
  const float* cw    = (const float*)d_in[5];
  const float* cb    = (const float*)d_in[6];

  float* mod     = (float*)d_ws;           // 524288 floats
  float* sums    = mod + 524288;           // 256 floats (raw |mod| sums)
  float* partial = sums + 256;             // 512 floats (mag partials)
  float* outp    = (float*)d_out;

  hipMemsetAsync(sums, 0, (256 + 512) * sizeof(float), stream);
  k1_gemm<<<512, 256, 0, stream>>>(x, Wt, Wg, mod);

  void* args[] = {&mod, &sums, &wstat, &wmod, &cw, &cb, &partial, &outp};
  hipLaunchCooperativeKernel((const void*)k234, dim3(512), dim3(256),
                             args, 0, stream);
}

// Round 9
// 149.819 us; speedup vs baseline: 1.6850x; 1.6850x over previous
//
#include <hip/hip_runtime.h>

typedef __bf16 bf16x8 __attribute__((ext_vector_type(8)));
typedef float floatx4 __attribute__((ext_vector_type(4)));

// split fp32 -> bf16 hi + bf16 lo (x ~= hi + lo, residual ~2^-17)
__device__ inline void cvt8_hl(const float* __restrict__ p, bf16x8& h, bf16x8& l){
  float4 v0 = *reinterpret_cast<const float4*>(p);
  float4 v1 = *reinterpret_cast<const float4*>(p + 4);
  float v[8] = {v0.x, v0.y, v0.z, v0.w, v1.x, v1.y, v1.z, v1.w};
  #pragma unroll
  for (int i = 0; i < 8; ++i) {
    __bf16 hi = (__bf16)v[i];
    h[i] = hi;
    l[i] = (__bf16)(v[i] - (float)hi);
  }
}

// ---------------------------------------------------------------------------
// K1 (round-0 proven, byte-identical; ~31us). ILP > TLP for this workload
// (R1/R3/R5 post-mortems). Do not touch.
// ---------------------------------------------------------------------------
__global__ __launch_bounds__(256) void k1_gemm(
    const float* __restrict__ x,
    const float* __restrict__ Wt,
    const float* __restrict__ Wg,
    float* __restrict__ mod)
{
  __shared__ float red[3][32][64];   // waves 1..3 partials, 24 KB
  const int tid  = threadIdx.x;
  const int wave = tid >> 6, lane = tid & 63;
  const int quad = lane >> 4, r16 = lane & 15;
  const int ff = blockIdx.x * 16 + r16;
  const int kb = wave * 256 + quad * 8;

  floatx4 accT[4], accG[4];
  #pragma unroll
  for (int m = 0; m < 4; ++m) { accT[m] = (floatx4)0.0f; accG[m] = (floatx4)0.0f; }

  const float* wt = Wt + ff * 1024 + kb;
  const float* wg = Wg + ff * 1024 + kb;
  const float* xp = x  + r16 * 1024 + kb;

  #pragma unroll
  for (int it = 0; it < 8; ++it) {
    const int ko = it * 32;
    bf16x8 bth, btl, bgh, bgl;
    cvt8_hl(wt + ko, bth, btl);
    cvt8_hl(wg + ko, bgh, bgl);
    #pragma unroll
    for (int mt = 0; mt < 4; ++mt) {
      bf16x8 ah, al;
      cvt8_hl(xp + mt * 16384 + ko, ah, al);
      accT[mt] = __builtin_amdgcn_mfma_f32_16x16x32_bf16(ah, bth, accT[mt], 0, 0, 0);
      accT[mt] = __builtin_amdgcn_mfma_f32_16x16x32_bf16(ah, btl, accT[mt], 0, 0, 0);
      accT[mt] = __builtin_amdgcn_mfma_f32_16x16x32_bf16(al, bth, accT[mt], 0, 0, 0);
      accG[mt] = __builtin_amdgcn_mfma_f32_16x16x32_bf16(ah, bgh, accG[mt], 0, 0, 0);
      accG[mt] = __builtin_amdgcn_mfma_f32_16x16x32_bf16(ah, bgl, accG[mt], 0, 0, 0);
      accG[mt] = __builtin_amdgcn_mfma_f32_16x16x32_bf16(al, bgh, accG[mt], 0, 0, 0);
    }
  }

  if (wave != 0) {
    #pragma unroll
    for (int mt = 0; mt < 4; ++mt)
      #pragma unroll
      for (int r = 0; r < 4; ++r) {
        red[wave - 1][mt * 4 + r][lane]      = accT[mt][r];
        red[wave - 1][16 + mt * 4 + r][lane] = accG[mt][r];
      }
  }
  __syncthreads();
  if (wave == 0) {
    #pragma unroll
    for (int mt = 0; mt < 4; ++mt) {
      #pragma unroll
      for (int r = 0; r < 4; ++r) {
        float t = accT[mt][r] + red[0][mt * 4 + r][lane]
                              + red[1][mt * 4 + r][lane]
                              + red[2][mt * 4 + r][lane];
        float g = accG[mt][r] + red[0][16 + mt * 4 + r][lane]
                              + red[1][16 + mt * 4 + r][lane]
                              + red[2][16 + mt * 4 + r][lane];
        float sig = 1.0f / (1.0f + __expf(-g));
        int b = mt * 16 + quad * 4 + r;          // C/D: row = quad*4 + reg
        mod[b * 8192 + ff] = t * g * sig;
      }
    }
  }
}

// ---------------------------------------------------------------------------
// K1b: s[b*4+k] = rsqrt(mean(|mod[b,k,:]|) + eps)  (round-0 proven body)
// + R9 weight-warming side-job: 65536 threads x 2 independent float4 reads
// pull the poison-evicted wmod (1MB) + wstat (1MB) into L2/L3, kept alive
// via empty asm (no DCE, no store). Overlaps k1b's existing latency; k2/k4's
// in-loop weight reads then hit cache (~200cyc) instead of cold HBM (~900).
// ---------------------------------------------------------------------------
__global__ __launch_bounds__(256) void k1b_scale(const float* __restrict__ mod,
                                                 const float* __restrict__ wmod,
                                                 const float* __restrict__ wstat,
                                                 float* __restrict__ s)
{
  const int row = blockIdx.x;
  const int tid = threadIdx.x;
  const float* p = mod + row * 2048;

  // --- warming loads: issue first, fully independent ---
  const int g = blockIdx.x * 256 + tid;          // 65536 threads
  const float4 wv = reinterpret_cast<const float4*>(wmod)[g];   // 65536 f4 = 1MB
  const float4 sv = reinterpret_cast<const float4*>(wstat)[g];  // 65536 f4 = 1MB
  float keep = wv.x + wv.y + wv.z + wv.w + sv.x + sv.y + sv.z + sv.w;
  asm volatile("" :: "v"(keep));                 // keep live, no side effect

  float sum = 0.0f;
  #pragma unroll
  for (int q = 0; q < 8; ++q) sum += fabsf(p[q * 256 + tid]);
  #pragma unroll
  for (int o = 1; o < 64; o <<= 1) sum += __shfl_xor(sum, o, 64);
  __shared__ float ls[4];
  if ((tid & 63) == 0) ls[tid >> 6] = sum;
  __syncthreads();
  if (tid == 0) {
    float t = ls[0] + ls[1] + ls[2] + ls[3];
    s[row] = rsqrtf(t * (1.0f / 2048.0f) + 1e-4f);
  }
}

// ---------------------------------------------------------------------------
// K2 (round-0 proven body, grid (64,8), direct partial write). R9 change:
// explicit #pragma unroll 8 on the 32-iteration loop so the (now L3-warm)
// wmod/wstat loads are hoisted 8 deep instead of serialized per iteration.
// ---------------------------------------------------------------------------
__global__ __launch_bounds__(256) void k2_mag(
    const float* __restrict__ mod, const float* __restrict__ s,
    const float* __restrict__ wstat,
    const float* __restrict__ wmod,
    const float* __restrict__ cw,
    const float* __restrict__ cb,
    float* __restrict__ partial)
{
  const int b = blockIdx.x, jc = blockIdx.y;
  const int tid = threadIdx.x;
  __shared__ __align__(16) float a_l[256 * 8];

  float weff[4]; float beff = 0.0f;
  #pragma unroll
  for (int r = 0; r < 4; ++r) {
    weff[r] = cw[r] + cw[4 + r] + cw[8 + r] + cw[12 + r];
    beff += cb[r];
  }
  const float s0 = s[b * 4 + 0], s1 = s[b * 4 + 1];
  const float* mb = mod + b * 8192;

  #pragma unroll
  for (int p = 0; p < 8; ++p) {              // p = (k,r); tid = i  (coalesced)
    int k = p >> 2, r = p & 3;
    float sc = (k ? s1 : s0) * weff[r];
    a_l[tid * 8 + p] = mb[k * 2048 + r * 512 + tid] * sc;
  }
  const int j = jc * 32 + (tid & 31);
  float bp[8];
  #pragma unroll
  for (int p = 0; p < 8; ++p) {
    int k = p >> 2, r = p & 3;
    bp[p] = mb[k * 2048 + r * 512 + 256 + j] * (k ? s1 : s0);
  }
  __syncthreads();

  const int ioff = tid >> 5;
  float acc = 0.0f;
  #pragma unroll 8
  for (int it = 0; it < 32; ++it) {
    const int i = it * 8 + ioff;
    const float4 av0 = *reinterpret_cast<const float4*>(&a_l[i * 8]);
    const float4 av1 = *reinterpret_cast<const float4*>(&a_l[i * 8 + 4]);
    float d0 = av0.x * bp[0] + av0.y * bp[1] + av0.z * bp[2] + av0.w * bp[3];
    float d1 = av1.x * bp[4] + av1.y * bp[5] + av1.z * bp[6] + av1.w * bp[7];
    const int ij = i * 256 + j;
    float m0 = wmod[ij] * (d0 + beff);
    float m1 = wmod[65536 + ij] * (d1 + beff);
    float2 a1 = *reinterpret_cast<const float2*>(wstat + 131072 + ij * 2);
    float re = a1.x * m0 - a1.y * m1;
    float im = a1.x * m1 - a1.y * m0;
    acc += sqrtf(re * re + im * im + 1e-4f);
  }
  #pragma unroll
  for (int o = 1; o < 64; o <<= 1) acc += __shfl_xor(acc, o, 64);
  __shared__ float wsum[4];
  if ((tid & 63) == 0) wsum[tid >> 6] = acc;
  __syncthreads();
  if (tid == 0) partial[b * 8 + jc] = wsum[0] + wsum[1] + wsum[2] + wsum[3];
}

// ---------------------------------------------------------------------------
// K4 (round-0 proven body, grid (64,8)). R9 change: unroll 2 -> 4 on the
// 16-iteration loop (each iteration's 6 weight loads are address-independent;
// deeper unroll = deeper MLP against warm-cache latency).
// ---------------------------------------------------------------------------
__global__ __launch_bounds__(256) void k4_out(
    const float* __restrict__ mod, const float* __restrict__ s,
    const float* __restrict__ wstat,
    const float* __restrict__ wmod,
    const float* __restrict__ cw,
    const float* __restrict__ cb,
    const float* __restrict__ partial,
    float* __restrict__ out)
{
  const int b = blockIdx.x, ibase = blockIdx.y * 32;
  const int tid = threadIdx.x;
  __shared__ __align__(16) float a_l[32 * 16];

  float weff[4]; float beff = 0.0f;
  #pragma unroll
  for (int r = 0; r < 4; ++r) {
    weff[r] = cw[r] + cw[4 + r] + cw[8 + r] + cw[12 + r];
    beff += cb[r];
  }
  float sk[4];
  #pragma unroll
  for (int k = 0; k < 4; ++k) sk[k] = s[b * 4 + k];
  const float* mb = mod + b * 8192;

  float tot = 0.0f;
  #pragma unroll
  for (int t = 0; t < 8; ++t) tot += partial[b * 8 + t];
  const float inv = rsqrtf(tot * (1.0f / 65536.0f) + 1e-4f);

  #pragma unroll
  for (int p = 0; p < 2; ++p) {
    int idx = p * 256 + tid;
    int il = idx & 31, kr = idx >> 5;
    int k = kr >> 2, r = kr & 3;
    a_l[il * 16 + kr] = mb[k * 2048 + r * 512 + ibase + il] * (sk[k] * weff[r]);
  }
  const int j = (tid & 127) * 2;
  const int ioff = tid >> 7;
  float bp0[16], bp1[16];
  #pragma unroll
  for (int kr = 0; kr < 16; ++kr) {
    int k = kr >> 2, r = kr & 3;
    float2 v = *reinterpret_cast<const float2*>(mb + k * 2048 + r * 512 + 256 + j);
    bp0[kr] = v.x * sk[k]; bp1[kr] = v.y * sk[k];
  }
  __syncthreads();

  #pragma unroll 4
  for (int it = 0; it < 16; ++it) {
    const int il = it * 2 + ioff;
    const int i = ibase + il;
    const float4 a0 = *reinterpret_cast<const float4*>(&a_l[il * 16]);
    const float4 a1 = *reinterpret_cast<const float4*>(&a_l[il * 16 + 4]);
    const float4 a2 = *reinterpret_cast<const float4*>(&a_l[il * 16 + 8]);
    const float4 a3 = *reinterpret_cast<const float4*>(&a_l[il * 16 + 12]);
    const int ij = i * 256 + j;
    const float2 wm0 = *reinterpret_cast<const float2*>(wmod + ij);
    const float2 wm1 = *reinterpret_cast<const float2*>(wmod + 65536 + ij);
    const float2 wm2 = *reinterpret_cast<const float2*>(wmod + 131072 + ij);
    const float2 wm3 = *reinterpret_cast<const float2*>(wmod + 196608 + ij);
    const float4 A0v = *reinterpret_cast<const float4*>(wstat + ij * 2);
    const float4 A1v = *reinterpret_cast<const float4*>(wstat + 131072 + ij * 2);
    float outv[2];
    #pragma unroll
    for (int e = 0; e < 2; ++e) {
      const float* bp = e ? bp1 : bp0;
      float d0 = a0.x * bp[0] + a0.y * bp[1] + a0.z * bp[2] + a0.w * bp[3];
      float d1 = a1.x * bp[4] + a1.y * bp[5] + a1.z * bp[6] + a1.w * bp[7];
      float d2 = a2.x * bp[8] + a2.y * bp[9] + a2.z * bp[10] + a2.w * bp[11];
      float d3 = a3.x * bp[12] + a3.y * bp[13] + a3.z * bp[14] + a3.w * bp[15];
      float m0 = (e ? wm0.y : wm0.x) * (d0 + beff);
      float m1 = (e ? wm1.y : wm1.x) * (d1 + beff);
      float m2 = (e ? wm2.y : wm2.x) * (d2 + beff);
      float m3 = (e ? wm3.y : wm3.x) * (d3 + beff);
      float A0r = e ? A0v.z : A0v.x;
      float A0i = e ? A0v.w : A0v.y;
      float A1r = e ? A1v.z : A1v.x;
      float A1i = e ? A1v.w : A1v.y;
      float re = A1r * m0 - A1i * m1;
      float im = A1r * m1 - A1i * m0;
      float mwre = A0r + re * inv;
      float mwim = A0i + im * inv;
      float rd = rsqrtf(m2 * m2 + m3 * m3 + 1e-4f);
      outv[e] = (mwre * m2 + mwim * m3) * rd;
    }
    *reinterpret_cast<float2*>(out + b * 65536 + ij) = make_float2(outv[0], outv[1]);
  }
}

extern "C" void kernel_launch(void* const* d_in, const int* in_sizes, int n_in,
                              void* d_out, int out_size, void* d_ws, size_t ws_size,
                              hipStream_t stream) {
  const float* x     = (const float*)d_in[0];
  const float* Wt    = (const float*)d_in[1];
  const float* Wg    = (const float*)d_in[2];
  const float* wstat = (const float*)d_in[3];
  const float* wmod  = (const float*)d_in[4];
  const float* cw    = (const float*)d_in[5];
  const float* cb    = (const float*)d_in[6];

  float* mod     = (float*)d_ws;           // 524288 floats
  float* sbuf    = mod + 524288;           // 256 floats
  float* partial = sbuf + 256;             // 512 floats

  k1_gemm  <<<512, 256, 0, stream>>>(x, Wt, Wg, mod);
  k1b_scale<<<256, 256, 0, stream>>>(mod, wmod, wstat, sbuf);
  k2_mag   <<<dim3(64, 8), 256, 0, stream>>>(mod, sbuf, wstat, wmod, cw, cb, partial);
  k4_out   <<<dim3(64, 8), 256, 0, stream>>>(mod, sbuf, wstat, wmod, cw, cb, partial,
                                             (float*)d_out);
}